// Round 2
// baseline (21676.010 us; speedup 1.0000x reference)
//
#include <hip/hip_runtime.h>
#include <hip/hip_cooperative_groups.h>
#include <cstddef>

namespace cg = cooperative_groups;

// Problem constants
#define S_ 512
#define B_ 64
#define I_ 256
#define H_ 1024

// ---------------------------------------------------------------------------
// Transpose: out[c*R + r] = in[r*C + c]  (used for Wx only)
// ---------------------------------------------------------------------------
__global__ __launch_bounds__(256) void transpose_k(const float* __restrict__ in,
                                                   float* __restrict__ out,
                                                   int R, int C) {
  __shared__ float t[32][33];
  int c0 = blockIdx.x * 32, r0 = blockIdx.y * 32;
  int x = threadIdx.x & 31, y = threadIdx.x >> 5;
  for (int i = 0; i < 32; i += 8)
    t[y + i][x] = in[(size_t)(r0 + y + i) * C + (c0 + x)];
  __syncthreads();
  for (int i = 0; i < 32; i += 8)
    out[(size_t)(c0 + y + i) * R + (r0 + x)] = t[x][y + i];
}

// ---------------------------------------------------------------------------
// xproj: out[m*H + j] = dot(x[m, :], WxT[:, j]) + bx[j]   (writes into d_out)
// ---------------------------------------------------------------------------
__global__ __launch_bounds__(256) void xproj_kernel(const float* __restrict__ x,
                                                    const float* __restrict__ WxT,
                                                    const float* __restrict__ bx,
                                                    float* __restrict__ out) {
  __shared__ float xs[4][I_];
  int tid = threadIdx.x;
  int j = blockIdx.x * 256 + tid;
  size_t m0 = (size_t)blockIdx.y * 4;
  const float* xrow = x + m0 * I_;
  for (int r = 0; r < 4; ++r) xs[r][tid] = xrow[(size_t)r * I_ + tid];
  __syncthreads();

  float bj = bx[j];
  float a0 = bj, a1 = bj, a2 = bj, a3 = bj;
  const float* wp = WxT + j;
  for (int k = 0; k < I_; k += 4) {
    float w0 = wp[(size_t)(k + 0) * H_];
    float w1 = wp[(size_t)(k + 1) * H_];
    float w2 = wp[(size_t)(k + 2) * H_];
    float w3 = wp[(size_t)(k + 3) * H_];
    float4 v0 = *(const float4*)&xs[0][k];
    float4 v1 = *(const float4*)&xs[1][k];
    float4 v2 = *(const float4*)&xs[2][k];
    float4 v3 = *(const float4*)&xs[3][k];
    a0 += w0 * v0.x + w1 * v0.y + w2 * v0.z + w3 * v0.w;
    a1 += w0 * v1.x + w1 * v1.y + w2 * v1.z + w3 * v1.w;
    a2 += w0 * v2.x + w1 * v2.y + w2 * v2.z + w3 * v2.w;
    a3 += w0 * v3.x + w1 * v3.y + w2 * v3.z + w3 * v3.w;
  }
  out[(m0 + 0) * H_ + j] = a0;
  out[(m0 + 1) * H_ + j] = a1;
  out[(m0 + 2) * H_ + j] = a2;
  out[(m0 + 3) * H_ + j] = a3;
}

__device__ __forceinline__ float fast_tanh(float z) {
  float e = __expf(-2.0f * fabsf(z));
  float r = (1.0f - e) * __builtin_amdgcn_rcpf(1.0f + e);
  return copysignf(r, z);
}

// ---------------------------------------------------------------------------
// Persistent cooperative RNN kernel. Grid = 256 blocks x 256 threads (1/CU).
// Block (jt = blk&15, ksg = blk>>4):
//   - owns Wh tile wLDS[k][j] = Wh[jt*64+j][ksg*64+k]  (16 KB, staged once)
//   - phase t:
//       (0) deferred write: out[t-1] <- h_{t-1} (jt==0 blocks, from registers)
//       (1) reduce: h_t[all 64 b][j in ksg-slice] = tanh(sum_ks part[ks][b][j]
//           + bh[j] + xproj_t[b][j]); keep in regs, stage transposed to hLDS
//       (2) GEMM: part_next[ksg][b][jt-slice] += wLDS . hLDS  (K=64 slice)
//       (3) grid.sync()
// partials double-buffered in ws: phase t reads buf[t&1], writes buf[(t+1)&1].
// ---------------------------------------------------------------------------
__global__ __launch_bounds__(256, 1) void rnn_persist(
    const float* __restrict__ Wh, const float* __restrict__ bh,
    float* __restrict__ out, float* __restrict__ partA,
    float* __restrict__ partB) {
  __shared__ float wLDS[64][64];  // [k_local][j_local]
  __shared__ float hLDS[64][64];  // [k_local][b]
  const int tid = threadIdx.x;
  const int jt = blockIdx.x & 15;
  const int ksg = blockIdx.x >> 4;

  // stage Wh tile (transposed), one-time
  for (int i = 0; i < 16; ++i) {
    int idx = i * 256 + tid;
    int jl = idx >> 6, kl = idx & 63;
    wLDS[kl][jl] = Wh[(size_t)(jt * 64 + jl) * H_ + (size_t)(ksg * 64 + kl)];
  }

  const int jq = tid & 15;   // j-quad index
  const int bq = tid >> 4;   // b-quad index
  const int j0 = jq << 2;    // local j base
  const int b0 = bq << 2;    // b base
  const int jg = ksg * 64 + j0;        // global j of reduce slice
  const int jgemm = jt * 64 + j0;      // global j of GEMM output slice

  const float4 bh4 = *(const float4*)(bh + jg);
  float hk[16];  // h_t[b0+bi][jg+ji], kept across phases for deferred write

  cg::grid_group grid = cg::this_grid();

  for (int t = 0; t < S_; ++t) {
    // (0) deferred h_{t-1} write (no reader of out[t-1] exists this phase)
    if (t > 0 && jt == 0) {
      for (int bi = 0; bi < 4; ++bi) {
        float4 v = make_float4(hk[bi * 4 + 0], hk[bi * 4 + 1],
                               hk[bi * 4 + 2], hk[bi * 4 + 3]);
        *(float4*)(out + (size_t)(t - 1) * B_ * H_ + (size_t)(b0 + bi) * H_ + jg) = v;
      }
    }

    // (1) reduce partials + bias + xproj -> h_t
    const float* pr = (t & 1) ? partB : partA;
    float z[4][4];
    for (int bi = 0; bi < 4; ++bi) {
      float4 xp = *(const float4*)(out + (size_t)t * B_ * H_ +
                                   (size_t)(b0 + bi) * H_ + jg);
      z[bi][0] = xp.x + bh4.x; z[bi][1] = xp.y + bh4.y;
      z[bi][2] = xp.z + bh4.z; z[bi][3] = xp.w + bh4.w;
    }
    if (t > 0) {
#pragma unroll 4
      for (int ks = 0; ks < 16; ++ks) {
        const float* base = pr + ((size_t)ks * B_ + b0) * H_ + jg;
        for (int bi = 0; bi < 4; ++bi) {
          float4 p = *(const float4*)(base + (size_t)bi * H_);
          z[bi][0] += p.x; z[bi][1] += p.y; z[bi][2] += p.z; z[bi][3] += p.w;
        }
      }
    }
    for (int bi = 0; bi < 4; ++bi)
      for (int ji = 0; ji < 4; ++ji)
        hk[bi * 4 + ji] = fast_tanh(z[bi][ji]);

    __syncthreads();  // everyone done with previous phase's hLDS
    for (int bi = 0; bi < 4; ++bi)
      for (int ji = 0; ji < 4; ++ji)
        hLDS[j0 + ji][b0 + bi] = hk[bi * 4 + ji];
    __syncthreads();

    // (2) GEMM partial for step t+1
    if (t < S_ - 1) {
      float* pw = ((t + 1) & 1) ? partB : partA;
      float a[4][4] = {{0.f}};
#pragma unroll 8
      for (int k = 0; k < 64; ++k) {
        float4 w4 = *(const float4*)&wLDS[k][j0];
        float4 h4 = *(const float4*)&hLDS[k][b0];
        a[0][0] += w4.x * h4.x; a[0][1] += w4.y * h4.x;
        a[0][2] += w4.z * h4.x; a[0][3] += w4.w * h4.x;
        a[1][0] += w4.x * h4.y; a[1][1] += w4.y * h4.y;
        a[1][2] += w4.z * h4.y; a[1][3] += w4.w * h4.y;
        a[2][0] += w4.x * h4.z; a[2][1] += w4.y * h4.z;
        a[2][2] += w4.z * h4.z; a[2][3] += w4.w * h4.z;
        a[3][0] += w4.x * h4.w; a[3][1] += w4.y * h4.w;
        a[3][2] += w4.z * h4.w; a[3][3] += w4.w * h4.w;
      }
      for (int bi = 0; bi < 4; ++bi) {
        float4 v = make_float4(a[bi][0], a[bi][1], a[bi][2], a[bi][3]);
        *(float4*)(pw + ((size_t)ksg * B_ + (size_t)(b0 + bi)) * H_ + jgemm) = v;
      }
    }

    grid.sync();
  }

  // final: write h_{S-1} to out[S-1] and to h_last slot
  if (jt == 0) {
    for (int bi = 0; bi < 4; ++bi) {
      float4 v = make_float4(hk[bi * 4 + 0], hk[bi * 4 + 1],
                             hk[bi * 4 + 2], hk[bi * 4 + 3]);
      *(float4*)(out + (size_t)(S_ - 1) * B_ * H_ + (size_t)(b0 + bi) * H_ + jg) = v;
      *(float4*)(out + (size_t)S_ * B_ * H_ + (size_t)(b0 + bi) * H_ + jg) = v;
    }
  }
}

// ---------------------------------------------------------------------------
// Fallback (round-1 path) if ws is too small for the partial buffers.
// ---------------------------------------------------------------------------
__global__ __launch_bounds__(256) void rnn_step(const float* __restrict__ WhT,
                                                const float* __restrict__ bh,
                                                float* __restrict__ out,
                                                int t, int first,
                                                float* __restrict__ out_last) {
  __shared__ float hs[4][H_];
  int tid = threadIdx.x;
  int lane = tid & 63, bl = tid >> 6;
  int j = blockIdx.x * 64 + lane;
  int b = blockIdx.y * 4 + bl;

  float acc = 0.f;
  if (!first) {
    const float4* hp4 =
        (const float4*)(out + (size_t)(t - 1) * B_ * H_ + (size_t)blockIdx.y * 4 * H_);
    float4* hs4 = (float4*)&hs[0][0];
    for (int i = tid; i < H_; i += 256) hs4[i] = hp4[i];
    __syncthreads();
    const float* wp = WhT + j;
#pragma unroll 2
    for (int k = 0; k < H_; k += 4) {
      float w0 = wp[(size_t)(k + 0) * H_];
      float w1 = wp[(size_t)(k + 1) * H_];
      float w2 = wp[(size_t)(k + 2) * H_];
      float w3 = wp[(size_t)(k + 3) * H_];
      float4 hv = *(const float4*)&hs[bl][k];
      acc += w0 * hv.x + w1 * hv.y + w2 * hv.z + w3 * hv.w;
    }
  }
  size_t idx = (size_t)b * H_ + j;
  float z = acc + bh[j] + out[(size_t)t * B_ * H_ + idx];
  float h = tanhf(z);
  out[(size_t)t * B_ * H_ + idx] = h;
  if (out_last) out_last[idx] = h;
}

// ---------------------------------------------------------------------------
// ws layout (floats):
//   WxT   : I_*H_          = 262144   (1 MB)
//   partA : 16*B_*H_       = 1048576  (4 MB)
//   partB : 16*B_*H_       = 1048576  (4 MB)
// total 9.4 MB. Fallback path needs only WxT + WhT (5 MB).
// ---------------------------------------------------------------------------
extern "C" void kernel_launch(void* const* d_in, const int* in_sizes, int n_in,
                              void* d_out, int out_size, void* d_ws, size_t ws_size,
                              hipStream_t stream) {
  const float* x  = (const float*)d_in[0];
  const float* Wx = (const float*)d_in[1];
  const float* bx = (const float*)d_in[2];
  const float* Wh = (const float*)d_in[3];
  const float* bh = (const float*)d_in[4];
  float* out = (float*)d_out;

  float* WxT   = (float*)d_ws;
  float* partA = WxT + (size_t)I_ * H_;
  float* partB = partA + (size_t)16 * B_ * H_;
  const size_t need = ((size_t)I_ * H_ + 2 * (size_t)16 * B_ * H_) * sizeof(float);

  hipLaunchKernelGGL(transpose_k, dim3(I_ / 32, H_ / 32), dim3(256), 0, stream,
                     Wx, WxT, H_, I_);
  hipLaunchKernelGGL(xproj_kernel, dim3(H_ / 256, (S_ * B_) / 4), dim3(256), 0, stream,
                     x, WxT, bx, out);

  if (ws_size >= need) {
    void* args[] = {(void*)&Wh, (void*)&bh, (void*)&out, (void*)&partA, (void*)&partB};
    hipLaunchCooperativeKernel((void*)rnn_persist, dim3(256), dim3(256), args, 0,
                               stream);
  } else {
    // fallback: per-step launches with WhT in ws (needs 5 MB)
    float* WhT = partA;  // reuse region: [H][H]
    hipLaunchKernelGGL(transpose_k, dim3(H_ / 32, H_ / 32), dim3(256), 0, stream,
                       Wh, WhT, H_, H_);
    for (int t = 0; t < S_; ++t) {
      float* out_last = (t == S_ - 1) ? out + (size_t)S_ * B_ * H_ : nullptr;
      hipLaunchKernelGGL(rnn_step, dim3(16, 16), dim3(256), 0, stream,
                         WhT, bh, out, t, (t == 0) ? 1 : 0, out_last);
    }
  }
}